// Round 1
// 139.450 us; speedup vs baseline: 1.0728x; 1.0728x over previous
//
#include <hip/hip_runtime.h>
#include <hip/hip_bf16.h>
#include <math.h>

#define NPIX 4096   // 64*64
#define NB 2

typedef __attribute__((ext_vector_type(8))) short short8;
typedef __attribute__((ext_vector_type(4))) short short4s;
typedef __attribute__((ext_vector_type(4))) float floatx4;

static __device__ inline short f2bf(float f) {
    union { float f; unsigned u; } v; v.f = f;
    unsigned r = (v.u + 0x7FFFu + ((v.u >> 16) & 1u)) >> 16;
    return (short)r;
}
static __device__ inline float bf2f(short s) {
    union { unsigned u; float f; } v;
    v.u = ((unsigned)(unsigned short)s) << 16;
    return v.f;
}
static __device__ inline unsigned pk2(float a, float b) {
    __hip_bfloat162 pk = __float22bfloat162_rn(make_float2(a, b));
    return *(unsigned*)&pk;
}

// ============ K0: prep bf16 B-layout weights (rows padded to 64 k, zeros) ======
// projwbf uses attention-output channel order: k = h*32 + cc (cc<24 real, rest 0)
__global__ void k_prepw(const float* __restrict__ qkvw, const float* __restrict__ fiw,
                        const float* __restrict__ fow, const float* __restrict__ projw,
                        short* __restrict__ qkvwbf, short* __restrict__ fiwbf,
                        short* __restrict__ fowbf, short* __restrict__ projwbf) {
    int idx = blockIdx.x * 256 + threadIdx.x;
    if (idx < 144 * 64) {
        int o = idx >> 6, c = idx & 63;
        qkvwbf[idx] = (c < 48) ? f2bf(qkvw[o * 48 + c]) : (short)0;
        return;
    }
    idx -= 144 * 64;
    if (idx < 192 * 64) {
        int o = idx >> 6, c = idx & 63;
        fiwbf[idx] = (c < 48) ? f2bf(fiw[o * 48 + c]) : (short)0;
        return;
    }
    idx -= 192 * 64;
    if (idx < 48 * 96) {
        fowbf[idx] = f2bf(fow[idx]);
        return;
    }
    idx -= 48 * 96;
    if (idx < 48 * 64) {
        int o = idx >> 6, c = idx & 63;
        int h = c >> 5, cc = c & 31;
        projwbf[idx] = (cc < 24) ? f2bf(projw[o * 48 + h * 24 + cc]) : (short)0;
    }
}

// ============ KB: fused LN1 + qkv 1x1 (MFMA, 3-row halo recompute) + dw3 +
//               l2norm/temp + Q/K/V pack.  grid (4, 64, NB), block 256.
// Pixel window: 18 px (16 out + x-halo) x 3 rows (y-halo), flattened pp = r*18+ix,
// padded to 64 rows for MFMA tiles. Out-of-image pixels forced to 0 AFTER bias
// (matches lax zero-pad of the conv1x1+bias feature map).
__global__ __launch_bounds__(256) void k_qkv_fused(
    const float* __restrict__ xin, const float* __restrict__ n1w, const float* __restrict__ n1b,
    const short* __restrict__ qkvwbf, const float* __restrict__ qkvb,
    const float* __restrict__ dww, const float* __restrict__ dwb,
    const float* __restrict__ temp,
    short* __restrict__ Qbf, short* __restrict__ Kbf, short* __restrict__ Vbf)
{
    int px0 = blockIdx.x * 16;
    int y = blockIdx.y, b = blockIdx.z;
    int t = threadIdx.x;
    int w = t >> 6, lane = t & 63, l15 = lane & 15, quad = lane >> 4;

    __shared__ __align__(16) short xn[64][72];    // LN output, 48 ch + 16 zero pad
    __shared__ short qkv[64][148];                // conv1x1 out bf16
    __shared__ float q2[16][148];                 // dw3 out fp32 (16 out px)
    __shared__ float red[4][64], redq[4][64];
    __shared__ float muS[64], rsS[64];
    __shared__ float dwwS[1296], dwbS[144];
    __shared__ short vmask[64];

    for (int u = t; u < 1296; u += 256) dwwS[u] = dww[u];
    if (t < 144) dwbS[t] = dwb[t];

    int pp = t & 63, cg = t >> 6;
    int rr = pp / 18, ix = pp - rr * 18;
    int yy = y + rr - 1, xpx = px0 - 1 + ix;
    bool pv = (pp < 54) && ((unsigned)yy < 64u) && ((unsigned)xpx < 64u);
    if (cg == 0) vmask[pp] = pv ? (short)1 : (short)0;

    float v[12]; float s = 0.f, sq = 0.f;
    if (pv) {
        size_t pbase = (size_t)(yy * 64 + xpx);
#pragma unroll
        for (int j = 0; j < 12; j++) {
            float vv = xin[((size_t)b * 48 + cg * 12 + j) * NPIX + pbase];
            v[j] = vv; s += vv; sq += vv * vv;
        }
    } else {
#pragma unroll
        for (int j = 0; j < 12; j++) v[j] = 0.f;
    }
    red[cg][pp] = s; redq[cg][pp] = sq;
    __syncthreads();
    if (t < 64) {
        float ss = red[0][t] + red[1][t] + red[2][t] + red[3][t];
        float qq = redq[0][t] + redq[1][t] + redq[2][t] + redq[3][t];
        float mu = ss * (1.f / 48.f);
        float var = qq * (1.f / 48.f) - mu * mu;
        muS[t] = mu; rsS[t] = rsqrtf(var + 1e-5f);
    }
    __syncthreads();
    {
        float mu = muS[pp], rs = rsS[pp];
#pragma unroll
        for (int j = 0; j < 12; j++) {
            int c = cg * 12 + j;
            xn[pp][c] = f2bf((v[j] - mu) * rs * n1w[c] + n1b[c]);
        }
        short8 z8 = {};
        if (cg == 0) *(short8*)&xn[pp][48] = z8;
        else if (cg == 1) *(short8*)&xn[pp][56] = z8;
    }
    __syncthreads();
    floatx4 zf = {0.f, 0.f, 0.f, 0.f};
    for (int job = w; job < 36; job += 4) {
        int pt = job / 9, ot = job % 9;
        short8 a0 = *(const short8*)&xn[pt * 16 + l15][quad * 8];
        short8 a1 = *(const short8*)&xn[pt * 16 + l15][32 + quad * 8];
        const short* wb = qkvwbf + (ot * 16 + l15) * 64;
        short8 b0 = *(const short8*)(wb + quad * 8);
        short8 b1 = *(const short8*)(wb + 32 + quad * 8);
        floatx4 c = __builtin_amdgcn_mfma_f32_16x16x32_bf16(a0, b0, zf, 0, 0, 0);
        c = __builtin_amdgcn_mfma_f32_16x16x32_bf16(a1, b1, c, 0, 0, 0);
        int oc = ot * 16 + l15;
        float bi = qkvb[oc];
#pragma unroll
        for (int r = 0; r < 4; r++) {
            int opp = pt * 16 + quad * 4 + r;
            qkv[opp][oc] = vmask[opp] ? f2bf(c[r] + bi) : (short)0;
        }
    }
    __syncthreads();
    {
        int i = t & 15, g = t >> 4;   // 16 groups x 9 channels
        for (int cc = 0; cc < 9; cc++) {
            int c = g * 9 + cc;
            const float* wp = dwwS + c * 9;
            float acc = dwbS[c];
#pragma unroll
            for (int dy = 0; dy < 3; dy++)
#pragma unroll
                for (int dx = 0; dx < 3; dx++)
                    acc += bf2f(qkv[dy * 18 + i + dx][c]) * wp[dy * 3 + dx];
            q2[i][c] = acc;
        }
    }
    __syncthreads();
    if (t < 128) {
        int i = t & 15, h = (t >> 4) & 1, sel = t >> 5;   // sel 0:q 1:k 2,3:v-halves
        int n = y * 64 + px0 + i;
        int bh = b * 2 + h;
        if (sel < 2) {
            float vv2[24]; float ss = 0.f;
            int base = sel * 48 + h * 24;
#pragma unroll
            for (int c = 0; c < 24; c++) { vv2[c] = q2[i][base + c]; ss += vv2[c] * vv2[c]; }
            float sc = ((sel == 0) ? temp[h] : 1.f) / fmaxf(sqrtf(ss), 1e-12f);
            short qs[32];
#pragma unroll
            for (int c = 0; c < 24; c++) qs[c] = f2bf(vv2[c] * sc);
#pragma unroll
            for (int c = 24; c < 32; c++) qs[c] = 0;
            short* dst = ((sel == 0) ? Qbf : Kbf) + ((size_t)bh * NPIX + n) * 32;
#pragma unroll
            for (int i8 = 0; i8 < 4; i8++) {
                short8 st;
#pragma unroll
                for (int j = 0; j < 8; j++) st[j] = qs[i8 * 8 + j];
                *(short8*)(dst + i8 * 8) = st;
            }
        } else {
            int half = sel - 2;
            int r5 = n & 31;
            int pos = (r5 < 16) ? ((r5 >> 2) * 8 + (r5 & 3))
                                : (((r5 & 15) >> 2) * 8 + (r5 & 3) + 4);
            int vcol = (n & ~31) + pos;
#pragma unroll
            for (int cc = 0; cc < 12; cc++) {
                int c = half * 12 + cc;
                Vbf[((size_t)bh * 32 + c) * NPIX + vcol] = f2bf(q2[i][96 + h * 24 + c]);
            }
            if (half == 1) {
#pragma unroll
                for (int c = 24; c < 32; c++)
                    Vbf[((size_t)bh * 32 + c) * NPIX + vcol] = 0;
            }
        }
    }
}

// ============ KC: MFMA flash attention, split-K INSIDE the block ===============
// grid (64 qt, 4 bh), block 1024 = 4 key-groups x 4 waves. Group g handles keys
// g*1024..+1023 with the verified transposed-score inner loop; partials combined
// in LDS, normalized, stored once as bf16 O[b][n][64] (ch = h*32+cc, cc<24 real).
__global__ __launch_bounds__(1024) void k_attn_mfma2(
    const short* __restrict__ Qbf, const short* __restrict__ Kbf,
    const short* __restrict__ Vbf, short* __restrict__ O)
{
    int qt = blockIdx.x, bh = blockIdx.y;
    int t = threadIdx.x;
    int tg = t & 255, g = t >> 8;
    int wloc = (t >> 6) & 3, lane = t & 63, l15 = lane & 15, quad = lane >> 4;

    __shared__ __align__(16) short tileK[4][2][64][40];
    __shared__ __align__(16) short tileV[4][2][32][72];
    __shared__ float Ocomb[4][64][33];
    __shared__ float Lcomb[4][64];

    int qrow0 = qt * 64 + wloc * 16;
    short8 bq = *(const short8*)(Qbf + ((size_t)bh * NPIX + qrow0 + l15) * 32 + quad * 8);

    int krow = tg >> 2, kseg = tg & 3;
    int vch = tg >> 3, vseg = tg & 7;
    const short* srcK = Kbf + ((size_t)bh * NPIX + krow) * 32 + kseg * 8;
    const short* srcV = Vbf + ((size_t)(bh * 32 + vch)) * NPIX + vseg * 8;

    int key0 = g * 1024;
    *(short8*)&tileK[g][0][krow][kseg * 8] = *(const short8*)(srcK + (size_t)key0 * 32);
    *(short8*)&tileV[g][0][vch][vseg * 8]  = *(const short8*)(srcV + key0);

    floatx4 zf = {0.f, 0.f, 0.f, 0.f};
    floatx4 o0 = zf, o1 = zf;
    float ls = 0.f;

    const int NKT = 16;
    for (int kt = 0; kt < NKT; kt++) {
        __syncthreads();
        int cur = kt & 1;
        short8 ldK = {}, ldV = {};
        if (kt < NKT - 1) {
            int kabs = key0 + (kt + 1) * 64;
            ldK = *(const short8*)(srcK + (size_t)kabs * 32);
            ldV = *(const short8*)(srcV + kabs);
        }
        short8 ka0 = *(const short8*)&tileK[g][cur][l15][quad * 8];
        short8 ka1 = *(const short8*)&tileK[g][cur][16 + l15][quad * 8];
        short8 ka2 = *(const short8*)&tileK[g][cur][32 + l15][quad * 8];
        short8 ka3 = *(const short8*)&tileK[g][cur][48 + l15][quad * 8];
        floatx4 s0 = __builtin_amdgcn_mfma_f32_16x16x32_bf16(ka0, bq, zf, 0, 0, 0);
        floatx4 s1 = __builtin_amdgcn_mfma_f32_16x16x32_bf16(ka1, bq, zf, 0, 0, 0);
        floatx4 s2 = __builtin_amdgcn_mfma_f32_16x16x32_bf16(ka2, bq, zf, 0, 0, 0);
        floatx4 s3 = __builtin_amdgcn_mfma_f32_16x16x32_bf16(ka3, bq, zf, 0, 0, 0);
        float e0[4], e1[4], e2[4], e3[4];
#pragma unroll
        for (int r = 0; r < 4; r++) {
            e0[r] = __expf(s0[r]); e1[r] = __expf(s1[r]);
            e2[r] = __expf(s2[r]); e3[r] = __expf(s3[r]);
            ls += (e0[r] + e1[r]) + (e2[r] + e3[r]);
        }
        short8 p01, p23;
        {
            unsigned* u01 = (unsigned*)&p01;
            unsigned* u23 = (unsigned*)&p23;
            u01[0] = pk2(e0[0], e0[1]); u01[1] = pk2(e0[2], e0[3]);
            u01[2] = pk2(e1[0], e1[1]); u01[3] = pk2(e1[2], e1[3]);
            u23[0] = pk2(e2[0], e2[1]); u23[1] = pk2(e2[2], e2[3]);
            u23[2] = pk2(e3[0], e3[1]); u23[3] = pk2(e3[2], e3[3]);
        }
        short8 va00 = *(const short8*)&tileV[g][cur][l15][quad * 8];
        short8 va01 = *(const short8*)&tileV[g][cur][l15][32 + quad * 8];
        short8 va10 = *(const short8*)&tileV[g][cur][16 + l15][quad * 8];
        short8 va11 = *(const short8*)&tileV[g][cur][16 + l15][32 + quad * 8];
        o0 = __builtin_amdgcn_mfma_f32_16x16x32_bf16(va00, p01, o0, 0, 0, 0);
        o0 = __builtin_amdgcn_mfma_f32_16x16x32_bf16(va01, p23, o0, 0, 0, 0);
        o1 = __builtin_amdgcn_mfma_f32_16x16x32_bf16(va10, p01, o1, 0, 0, 0);
        o1 = __builtin_amdgcn_mfma_f32_16x16x32_bf16(va11, p23, o1, 0, 0, 0);
        if (kt < NKT - 1) {
            *(short8*)&tileK[g][1 - cur][krow][kseg * 8] = ldK;
            *(short8*)&tileV[g][1 - cur][vch][vseg * 8]  = ldV;
        }
    }
    ls += __shfl_xor(ls, 16, 64);
    ls += __shfl_xor(ls, 32, 64);
    int qi = wloc * 16 + l15;
#pragma unroll
    for (int r = 0; r < 4; r++) {
        Ocomb[g][qi][quad * 4 + r]      = o0[r];
        Ocomb[g][qi][16 + quad * 4 + r] = o1[r];
    }
    if (quad == 0) Lcomb[g][qi] = ls;
    __syncthreads();
    {
        int qq = t >> 4, cp = t & 15;
        float l4 = Lcomb[0][qq] + Lcomb[1][qq] + Lcomb[2][qq] + Lcomb[3][qq];
        float inv = 1.f / l4;
        float sa = (Ocomb[0][qq][2 * cp] + Ocomb[1][qq][2 * cp] +
                    Ocomb[2][qq][2 * cp] + Ocomb[3][qq][2 * cp]) * inv;
        float sb = (Ocomb[0][qq][2 * cp + 1] + Ocomb[1][qq][2 * cp + 1] +
                    Ocomb[2][qq][2 * cp + 1] + Ocomb[3][qq][2 * cp + 1]) * inv;
        int b = bh >> 1, h = bh & 1;
        int n = qt * 64 + qq;
        *(unsigned*)(O + ((size_t)b * NPIX + n) * 64 + h * 32 + 2 * cp) = pk2(sa, sb);
    }
}

// ============ KD: fused proj(+res, x1 in LDS) + LN2 + fi + dw3 + gate + fo + res
// grid (4, 64, NB), block 256. Same 18x3-window recompute scheme as KB.
__global__ __launch_bounds__(256) void k_tail_fused(
    const float* __restrict__ xin, const short* __restrict__ O,
    const short* __restrict__ projwbf, const float* __restrict__ projb,
    const float* __restrict__ n2w, const float* __restrict__ n2b,
    const short* __restrict__ fiwbf, const float* __restrict__ fib,
    const float* __restrict__ fdww, const float* __restrict__ fdwb,
    const short* __restrict__ fowbf, const float* __restrict__ fob,
    float* __restrict__ out)
{
    int px0 = blockIdx.x * 16;
    int y = blockIdx.y, b = blockIdx.z;
    int t = threadIdx.x;
    int w = t >> 6, lane = t & 63, l15 = lane & 15, quad = lane >> 4;

    __shared__ float x1s[64][53];
    __shared__ __align__(16) short xn2[64][72];
    __shared__ short ypre[56][196];
    __shared__ __align__(16) short yv[16][104];
    __shared__ float red[4][64], redq[4][64];
    __shared__ float muS[64], rsS[64];
    __shared__ float fdwwS[1728], fdwbS[192];
    __shared__ short vmask[64];
    __shared__ int nidx[64];

    for (int u = t; u < 1728; u += 256) fdwwS[u] = fdww[u];
    if (t < 192) fdwbS[t] = fdwb[t];
    if (t < 64) {
        int rr = t / 18, ix = t - rr * 18;
        int yy = y + rr - 1, xpx = px0 - 1 + ix;
        bool pv = (t < 54) && ((unsigned)yy < 64u) && ((unsigned)xpx < 64u);
        vmask[t] = pv ? (short)1 : (short)0;
        int n = yy * 64 + xpx;
        n = n < 0 ? 0 : (n > 4095 ? 4095 : n);
        nidx[t] = n;
    }
    __syncthreads();

    floatx4 zf = {0.f, 0.f, 0.f, 0.f};
    // proj + residual into LDS (invalid pixels: finite garbage, masked later)
    for (int job = w; job < 12; job += 4) {
        int pt = job / 3, ot = job % 3;
        const short* oa = O + ((size_t)b * NPIX + nidx[pt * 16 + l15]) * 64;
        short8 a0 = *(const short8*)(oa + quad * 8);
        short8 a1 = *(const short8*)(oa + 32 + quad * 8);
        const short* wb = projwbf + (ot * 16 + l15) * 64;
        short8 b0 = *(const short8*)(wb + quad * 8);
        short8 b1 = *(const short8*)(wb + 32 + quad * 8);
        floatx4 c = __builtin_amdgcn_mfma_f32_16x16x32_bf16(a0, b0, zf, 0, 0, 0);
        c = __builtin_amdgcn_mfma_f32_16x16x32_bf16(a1, b1, c, 0, 0, 0);
        int oc = ot * 16 + l15;
        float bi = projb[oc];
#pragma unroll
        for (int r = 0; r < 4; r++) {
            int opp = pt * 16 + quad * 4 + r;
            x1s[opp][oc] = xin[((size_t)b * 48 + oc) * NPIX + nidx[opp]] + c[r] + bi;
        }
    }
    __syncthreads();
    // LN2
    int pp = t & 63, cg = t >> 6;
    {
        float v[12]; float s = 0.f, sq = 0.f;
#pragma unroll
        for (int j = 0; j < 12; j++) {
            float vv = x1s[pp][cg * 12 + j];
            v[j] = vv; s += vv; sq += vv * vv;
        }
        red[cg][pp] = s; redq[cg][pp] = sq;
        __syncthreads();
        if (t < 64) {
            float ss = red[0][t] + red[1][t] + red[2][t] + red[3][t];
            float qq = redq[0][t] + redq[1][t] + redq[2][t] + redq[3][t];
            float mu = ss * (1.f / 48.f);
            float var = qq * (1.f / 48.f) - mu * mu;
            muS[t] = mu; rsS[t] = rsqrtf(var + 1e-5f);
        }
        __syncthreads();
        float mu = muS[pp], rs = rsS[pp];
#pragma unroll
        for (int j = 0; j < 12; j++) {
            int c = cg * 12 + j;
            xn2[pp][c] = f2bf((v[j] - mu) * rs * n2w[c] + n2b[c]);
        }
        short8 z8 = {};
        if (cg == 0) *(short8*)&xn2[pp][48] = z8;
        else if (cg == 1) *(short8*)&xn2[pp][56] = z8;
    }
    __syncthreads();
    // fi 1x1 (192 oc), zero-masked outside the image (conv zero-pads after bias)
    for (int job = w; job < 48; job += 4) {
        int pt = job / 12, ot = job % 12;
        short8 a0 = *(const short8*)&xn2[pt * 16 + l15][quad * 8];
        short8 a1 = *(const short8*)&xn2[pt * 16 + l15][32 + quad * 8];
        const short* wb = fiwbf + (ot * 16 + l15) * 64;
        short8 b0 = *(const short8*)(wb + quad * 8);
        short8 b1 = *(const short8*)(wb + 32 + quad * 8);
        floatx4 c = __builtin_amdgcn_mfma_f32_16x16x32_bf16(a0, b0, zf, 0, 0, 0);
        c = __builtin_amdgcn_mfma_f32_16x16x32_bf16(a1, b1, c, 0, 0, 0);
        int oc = ot * 16 + l15;
        float bi = fib[oc];
#pragma unroll
        for (int r = 0; r < 4; r++) {
            int opp = pt * 16 + quad * 4 + r;
            if (opp < 56) ypre[opp][oc] = vmask[opp] ? f2bf(c[r] + bi) : (short)0;
        }
    }
    __syncthreads();
    // dw3 + GELU gate
    {
        int i = t & 15, gg = t >> 4;   // 16 groups x 6 channel-pairs
        for (int cc = 0; cc < 6; cc++) {
            int c = gg * 6 + cc;
            const float* wp  = fdwwS + c * 9;
            const float* wp2 = fdwwS + (c + 96) * 9;
            float a = fdwbS[c], g2v = fdwbS[c + 96];
#pragma unroll
            for (int dy = 0; dy < 3; dy++)
#pragma unroll
                for (int dx = 0; dx < 3; dx++) {
                    int ppi = dy * 18 + i + dx;
                    a   += bf2f(ypre[ppi][c])      * wp[dy * 3 + dx];
                    g2v += bf2f(ypre[ppi][c + 96]) * wp2[dy * 3 + dx];
                }
            float ge = 0.5f * a * (1.f + erff(a * 0.70710678118654752f));
            yv[i][c] = f2bf(ge * g2v);
        }
        short8 z8 = {};
        if (gg == 0) *(short8*)&yv[i][96] = z8;
    }
    __syncthreads();
    // fo 1x1 + final residual from LDS x1
    if (w < 3) {
        floatx4 c = zf;
#pragma unroll
        for (int k = 0; k < 3; k++) {
            short8 a  = *(const short8*)&yv[l15][k * 32 + quad * 8];
            short8 bb = *(const short8*)(fowbf + (w * 16 + l15) * 96 + k * 32 + quad * 8);
            c = __builtin_amdgcn_mfma_f32_16x16x32_bf16(a, bb, c, 0, 0, 0);
        }
        int oc = w * 16 + l15;
        float bi = fob[oc];
#pragma unroll
        for (int r = 0; r < 4; r++) {
            int i = quad * 4 + r;
            size_t idx = ((size_t)b * 48 + oc) * NPIX + y * 64 + px0 + i;
            out[idx] = x1s[19 + i][oc] + c[r] + bi;
        }
    }
}

extern "C" void kernel_launch(void* const* d_in, const int* in_sizes, int n_in,
                              void* d_out, int out_size, void* d_ws, size_t ws_size,
                              hipStream_t stream) {
    const float* x       = (const float*)d_in[0];
    const float* n1w     = (const float*)d_in[1];
    const float* n1b     = (const float*)d_in[2];
    const float* qkv_w   = (const float*)d_in[3];
    const float* qkv_b   = (const float*)d_in[4];
    const float* qkvdw_w = (const float*)d_in[5];
    const float* qkvdw_b = (const float*)d_in[6];
    const float* temp    = (const float*)d_in[7];
    const float* proj_w  = (const float*)d_in[8];
    const float* proj_b  = (const float*)d_in[9];
    const float* n2w     = (const float*)d_in[10];
    const float* n2b     = (const float*)d_in[11];
    const float* fi_w    = (const float*)d_in[12];
    const float* fi_b    = (const float*)d_in[13];
    const float* fdw_w   = (const float*)d_in[14];
    const float* fdw_b   = (const float*)d_in[15];
    const float* fo_w    = (const float*)d_in[16];
    const float* fo_b    = (const float*)d_in[17];

    short* sws = (short*)d_ws;
    short* Qbf     = sws;                    // 4*4096*32 = 524288 sh
    short* Kbf     = Qbf + 524288;           // 524288 sh
    short* Vbf     = Kbf + 524288;           // 524288 sh
    short* Obuf    = Vbf + 524288;           // 2*4096*64 = 524288 sh
    short* qkvwbf  = Obuf + 524288;          // 9216 sh
    short* fiwbf   = qkvwbf + 9216;          // 12288 sh
    short* fowbf   = fiwbf + 12288;          // 4608 sh
    short* projwbf = fowbf + 4608;           // 3072 sh

    {   // weights -> bf16 B-layout
        int total = 144 * 64 + 192 * 64 + 48 * 96 + 48 * 64;
        k_prepw<<<(total + 255) / 256, 256, 0, stream>>>(qkv_w, fi_w, fo_w, proj_w,
                                                         qkvwbf, fiwbf, fowbf, projwbf);
    }
    {   // LN1 + qkv 1x1 + dw3 + l2norm/temp + pack
        dim3 g(4, 64, NB);
        k_qkv_fused<<<g, 256, 0, stream>>>(x, n1w, n1b, qkvwbf, qkv_b,
                                           qkvdw_w, qkvdw_b, temp, Qbf, Kbf, Vbf);
    }
    {   // attention with in-block split-K combine
        dim3 g(64, 4);
        k_attn_mfma2<<<g, 1024, 0, stream>>>(Qbf, Kbf, Vbf, Obuf);
    }
    {   // proj + res + LN2 + fi + dw3 + gate + fo + res
        dim3 g(4, 64, NB);
        k_tail_fused<<<g, 256, 0, stream>>>(x, Obuf, projwbf, proj_b, n2w, n2b,
                                            fiwbf, fi_b, fdw_w, fdw_b, fowbf, fo_b,
                                            (float*)d_out);
    }
}